// Round 6
// baseline (1591.068 us; speedup 1.0000x reference)
//
#include <hip/hip_runtime.h>
#include <stdint.h>
#include <stddef.h>

#define NBATCH 32
#define HW     16384      // 128*128
#define CCH    128

typedef short bf16x8 __attribute__((ext_vector_type(8)));
typedef float f32x4  __attribute__((ext_vector_type(4)));

__device__ __forceinline__ float bf2f(unsigned short u){
    union { unsigned int i; float f; } v; v.i = ((unsigned int)u) << 16; return v.f;
}
__device__ __forceinline__ unsigned short f2bf(float f){
    union { float f; unsigned int i; } v; v.f = f;
    unsigned int x = v.i;
    x += 0x7fffu + ((x >> 16) & 1u);   // round-to-nearest-even
    return (unsigned short)(x >> 16);
}
__device__ __forceinline__ unsigned int h16(uint2 u, int j){
    unsigned int v = (j & 2) ? u.y : u.x;
    return (j & 1) ? (v >> 16) : (v & 0xffffu);
}
__device__ __forceinline__ void gl_lds16(const unsigned short* g, unsigned short* l){
    __builtin_amdgcn_global_load_lds(
        reinterpret_cast<const __attribute__((address_space(1))) unsigned int*>(
            reinterpret_cast<uintptr_t>(g)),
        reinterpret_cast<__attribute__((address_space(3))) unsigned int*>(
            reinterpret_cast<uintptr_t>(l)),
        16, 0, 0);
}
template<int N> __device__ __forceinline__ void vmwait(){
    asm volatile("s_waitcnt vmcnt(%0)" :: "n"(N) : "memory");
}

// ---------------------------------------------------------------- weight prep:
// per conv: [NCH][2(hi/lo)][128][32] bf16, K-swizzled: stored col cs holds logical
// c = ((cs>>3)^((row>>1)&3))*8 + (cs&7). Chunks of 8192 shorts (16 KB).
// segments (shorts): wa1@0(1) wb1@8192(1) wc1@16384(5) wa2@57344(4) wb2@90112(4)
// wc2@122880(8) wa3@188416(4) wb3@221184(4) wc3@253952(8). total 319488.
#define WPREP_TOTAL 319488
__global__ __launch_bounds__(256) void k_prep(
    const float* __restrict__ w11, const float* __restrict__ w12, const float* __restrict__ w13,
    const float* __restrict__ w21, const float* __restrict__ w22, const float* __restrict__ w23,
    const float* __restrict__ w31, const float* __restrict__ w32, const float* __restrict__ w33,
    unsigned short* __restrict__ wp)
{
    int i = blockIdx.x*256 + threadIdx.x;
    if(i >= WPREP_TOTAL) return;
    const float* src; int K, mode, base;   // mode: 0=normal 1=dup16 2=wc1
    if     (i < 8192)  { src=w11; K=16;  mode=1; base=0;      }
    else if(i < 16384) { src=w12; K=16;  mode=1; base=8192;   }
    else if(i < 57344) { src=w13; K=144; mode=2; base=16384;  }
    else if(i < 90112) { src=w21; K=128; mode=0; base=57344;  }
    else if(i < 122880){ src=w22; K=128; mode=0; base=90112;  }
    else if(i < 188416){ src=w23; K=256; mode=0; base=122880; }
    else if(i < 221184){ src=w31; K=128; mode=0; base=188416; }
    else if(i < 253952){ src=w32; K=128; mode=0; base=221184; }
    else               { src=w33; K=256; mode=0; base=253952; }
    int j  = i - base;
    int ck = j >> 13;
    int jj = j & 8191;
    int half = jj >> 12;
    int row  = (jj >> 5) & 127;
    int cs   = jj & 31;
    int s    = (row >> 1) & 3;
    int c    = (((cs >> 3) ^ s) << 3) | (cs & 7);   // logical k within chunk
    int col  = (mode==1) ? (c & 15)
             : (mode==2) ? (ck < 4 ? ck*32 + c : 128 + (c & 15))
             :             ck*32 + c;
    float v = src[row*K + col];
    unsigned short hi = f2bf(v);
    wp[i] = half ? f2bf(v - bf2f(hi)) : hi;
}

// ---------------------------------------------------------------- X2 -> swizzled hw-major hi/lo:
// X2b[b][ht(64)][256 hwin][32 c] bf16; c 0-15 = hi, 16-31 = lo; K-swizzled like W.
__global__ __launch_bounds__(256) void k_xprep(const float* __restrict__ X2, unsigned short* __restrict__ X2b){
    const int ht = blockIdx.x, b = blockIdx.y, t = threadIdx.x;
    const float* src = X2 + (size_t)b*16*HW + ht*256 + t;
    unsigned short hv[16], lv[16];
    #pragma unroll
    for(int c=0;c<16;c++){
        float v = src[(size_t)c*HW];
        hv[c] = f2bf(v);
        lv[c] = f2bf(v - bf2f(hv[c]));
    }
    const int s = (t >> 1) & 3;
    unsigned short* dst = X2b + ((size_t)b*64 + ht)*8192 + t*32;
    #pragma unroll
    for(int g=0; g<4; g++){
        const unsigned short* q = (g < 2) ? &hv[(g&1)*8] : &lv[(g&1)*8];
        uint4 pk;
        pk.x = (unsigned int)q[0] | ((unsigned int)q[1]<<16);
        pk.y = (unsigned int)q[2] | ((unsigned int)q[3]<<16);
        pk.z = (unsigned int)q[4] | ((unsigned int)q[5]<<16);
        pk.w = (unsigned int)q[6] | ((unsigned int)q[7]<<16);
        *reinterpret_cast<uint4*>(dst + ((g ^ s) << 3)) = pk;
    }
}

// ---------------------------------------------------------------- Msum = M[:,0]+M[:,1]
__global__ __launch_bounds__(256) void k_msum(const float* __restrict__ M, float* __restrict__ msum){
    int i = blockIdx.x*256 + threadIdx.x;
    int b = i >> 14, hw = i & (HW-1);
    msum[i] = M[(size_t)b*2*HW + hw] + M[(size_t)b*2*HW + HW + hw];
}

// ---------------------------------------------------------------- unified conv GEMM (512 thr, 8 waves 2x4)
// Out[128 ch][256 hw-tile] = relu((W @ concat(P, X) + bias) * Msum).
// W,X staged via global_load_lds from pre-swizzled layouts; P reg-staged.
// CC: fused diag-reduce; STORE: write swizzled hw-major output. !CC: z picks wa/wb -> plain [c][hw].
template<int NCHP, int NCHX, bool CC, bool GX, bool STORE>
__global__ __launch_bounds__(512,4) void k_conv(
    const unsigned short* __restrict__ Wp,
    const unsigned short* __restrict__ Psrc,   // plain [bi][128][HW]
    const unsigned short* __restrict__ Xsrc,   // swz [b][ht][NCHX][8192]
    const float* __restrict__ biasA, const float* __restrict__ biasB,
    const float* __restrict__ msum, const float* __restrict__ Mfull,
    unsigned short* __restrict__ OutA, unsigned short* __restrict__ OutB,
    float* __restrict__ xo, int b0, int xo_off)
{
    constexpr int NCH = NCHP + NCHX;
    __shared__ unsigned short Wl[16384];   // 2 x [2][128][32]
    __shared__ unsigned short Xl[16384];   // 2 x [256][32]
    const int bi = blockIdx.y, bg = b0 + bi, ht = blockIdx.x;
    const int z = CC ? 0 : blockIdx.z;
    const int t = threadIdx.x;
    const int w = t >> 6, lane = t & 63;
    const int lr = lane & 15, lg = lane >> 4;
    const int wm = w & 1, wn = w >> 1;           // rows wm*64.., cols wn*64..
    const int cg = t & 7, h4 = t >> 3;           // P staging mapping
    const unsigned short* Wseg  = Wp + (size_t)z*NCH*8192;
    const unsigned short* pbase = Psrc + (size_t)bi*CCH*HW;
    const unsigned short* xbase = Xsrc + ((size_t)(GX ? bg : bi)*64 + ht)*NCHX*8192;

    f32x4 acc[4][4];
    #pragma unroll
    for(int mf=0; mf<4; mf++)
        #pragma unroll
        for(int nf=0; nf<4; nf++) acc[mf][nf] = (f32x4){0.f,0.f,0.f,0.f};

    uint2 pr[2][4];

    auto stage = [&](int ck){
        { const unsigned short* s = Wseg + (size_t)ck*8192 + t*8;
          unsigned short* d = &Wl[(ck&1)*8192] + t*8;
          gl_lds16(s, d); gl_lds16(s + 4096, d + 4096); }
        if(ck < NCHP){
            const unsigned short* s = pbase + (size_t)(ck*32 + cg*4)*HW + ht*256 + h4*4;
            #pragma unroll
            for(int i2=0;i2<4;i2++) pr[ck&1][i2] = *reinterpret_cast<const uint2*>(s + (size_t)i2*HW);
        } else {
            const unsigned short* s = xbase + (size_t)(ck - NCHP)*8192 + t*8;
            unsigned short* d = &Xl[(ck&1)*8192] + t*8;
            gl_lds16(s, d); gl_lds16(s + 4096, d + 4096);
        }
    };
    auto writeP = [&](int ck){
        #pragma unroll
        for(int j=0;j<4;j++){
            int hwin = h4*4 + j;
            int sx = (hwin >> 1) & 3;
            int pos = (((cg>>1) ^ sx) << 3) + (cg&1)*4;
            uint2 v;
            v.x = h16(pr[ck&1][0],j) | (h16(pr[ck&1][1],j) << 16);
            v.y = h16(pr[ck&1][2],j) | (h16(pr[ck&1][3],j) << 16);
            *reinterpret_cast<uint2*>(&Xl[(ck&1)*8192] + hwin*32 + pos) = v;
        }
    };
    auto compute = [&](int buf){
        const unsigned short* Wb = &Wl[buf*8192];
        const unsigned short* Xb = &Xl[buf*8192];
        #pragma unroll
        for(int hp=0; hp<2; hp++){              // two mf-half passes (VGPR pressure)
            bf16x8 ah[2], al[2];
            #pragma unroll
            for(int m2=0;m2<2;m2++){
                int row = wm*64 + (hp*2+m2)*16 + lr;
                int off = row*32 + ((lg ^ ((row>>1)&3)) << 3);
                ah[m2] = *reinterpret_cast<const bf16x8*>(&Wb[off]);
                al[m2] = *reinterpret_cast<const bf16x8*>(&Wb[4096 + off]);
            }
            #pragma unroll
            for(int nf=0;nf<4;nf++){
                int hwin = wn*64 + nf*16 + lr;
                bf16x8 bfr = *reinterpret_cast<const bf16x8*>(&Xb[hwin*32 + ((lg ^ ((hwin>>1)&3)) << 3)]);
                #pragma unroll
                for(int m2=0;m2<2;m2++){
                    acc[hp*2+m2][nf] = __builtin_amdgcn_mfma_f32_16x16x32_bf16(ah[m2], bfr, acc[hp*2+m2][nf], 0,0,0);
                    acc[hp*2+m2][nf] = __builtin_amdgcn_mfma_f32_16x16x32_bf16(al[m2], bfr, acc[hp*2+m2][nf], 0,0,0);
                }
            }
        }
    };

    stage(0);
    #pragma unroll
    for(int i=0;i<NCH;i++){
        if(i+1 < NCH) stage(i+1);
        if(i+1 < NCH){ if(i+1 < NCHP) vmwait<6>(); else vmwait<4>(); }
        else vmwait<0>();
        __builtin_amdgcn_sched_barrier(0);
        if(i < NCHP) writeP(i);
        asm volatile("s_waitcnt lgkmcnt(0)" ::: "memory");
        __builtin_amdgcn_s_barrier();
        compute(i & 1);
        __builtin_amdgcn_s_barrier();
    }

    // ---- epilogue
    float msv[4], mdv[4];
    #pragma unroll
    for(int nf=0; nf<4; nf++){
        int hwi = ht*256 + wn*64 + nf*16 + lr;
        msv[nf] = msum[(size_t)bg*HW + hwi];
        if constexpr (CC) mdv[nf] = Mfull[(size_t)bg*2*HW + hwi];
    }
    if constexpr (!CC){
        const float* bias = z ? biasB : biasA;
        unsigned short* dst = (z ? OutB : OutA) + (size_t)bi*CCH*HW;
        #pragma unroll
        for(int mf=0; mf<4; mf++){
            #pragma unroll
            for(int reg=0; reg<4; reg++){
                int row = wm*64 + mf*16 + lg*4 + reg;
                float bv = bias[row];
                #pragma unroll
                for(int nf=0; nf<4; nf++){
                    float v2 = (acc[mf][nf][reg] + bv) * msv[nf];
                    v2 = v2 > 0.f ? v2 : 0.f;
                    dst[(size_t)row*HW + ht*256 + wn*64 + nf*16 + lr] = f2bf(v2);
                }
            }
        }
    } else {
        #pragma unroll
        for(int mf=0; mf<4; mf++){
            const int ckO = wm*2 + (mf>>1);
            const int c0  = (mf&1)*16 + lg*4;        // ch within 32-chunk
            float red[4] = {0.f,0.f,0.f,0.f};
            #pragma unroll
            for(int nf=0; nf<4; nf++){
                int hwin = wn*64 + nf*16 + lr;
                float vv[4];
                #pragma unroll
                for(int reg=0; reg<4; reg++){
                    int row = wm*64 + mf*16 + lg*4 + reg;
                    float v2 = (acc[mf][nf][reg] + biasA[row]) * msv[nf];
                    v2 = v2 > 0.f ? v2 : 0.f;
                    vv[reg] = v2;
                    red[reg] += v2 * mdv[nf];
                }
                if constexpr (STORE){
                    int sx = (hwin>>1)&3;
                    int pos = ((((c0>>3) ^ sx) << 3)) + (c0 & 7);
                    uint2 pk;
                    pk.x = (unsigned int)f2bf(vv[0]) | ((unsigned int)f2bf(vv[1])<<16);
                    pk.y = (unsigned int)f2bf(vv[2]) | ((unsigned int)f2bf(vv[3])<<16);
                    *reinterpret_cast<uint2*>(OutA + (((size_t)bi*64 + ht)*4 + ckO)*8192 + hwin*32 + pos) = pk;
                }
            }
            #pragma unroll
            for(int reg=0; reg<4; reg++){
                float r = red[reg];
                r += __shfl_xor(r, 1);
                r += __shfl_xor(r, 2);
                r += __shfl_xor(r, 4);
                r += __shfl_xor(r, 8);
                if(lr == 0)
                    atomicAdd(&xo[(size_t)bg*384 + xo_off + wm*64 + mf*16 + lg*4 + reg], r);
            }
        }
    }
}

// ---------------------------------------------------------------- batched spatial matmul:
// P[b,c] = (A[b,c] @ B[b,c]) * Msum[b]  (128x128x128 bf16 MFMA; P aliases A)
__global__ __launch_bounds__(256) void k_bmm(
    const unsigned short* __restrict__ A, const unsigned short* __restrict__ Bm,
    const float* __restrict__ msum, unsigned short* __restrict__ P, int b0)
{
    __shared__ unsigned short Bs[128*136];
    const int m  = blockIdx.x;
    const int bi = m >> 7;
    const int bg = b0 + bi;
    const unsigned short* Ab = A  + (size_t)m*HW;
    const unsigned short* Bb = Bm + (size_t)m*HW;
    unsigned short*       Pb = P  + (size_t)m*HW;
    const float* ms = msum + (size_t)bg*HW;
    const int t = threadIdx.x;
    const int w  = t >> 6;
    const int l  = t & 63;
    const int lr = l & 15;
    const int lg = l >> 4;

    bf16x8 af[4][2];
    #pragma unroll
    for(int kk=0;kk<4;kk++)
        #pragma unroll
        for(int rt=0;rt<2;rt++)
            af[kk][rt] = *reinterpret_cast<const bf16x8*>(Ab + (size_t)(w*32 + rt*16 + lr)*128 + kk*32 + lg*8);

    #pragma unroll
    for(int it=0; it<8; it++){
        int task = it*256 + t;
        int j  = task & 127;
        int kg = task >> 7;
        unsigned short v[8];
        #pragma unroll
        for(int i=0;i<8;i++) v[i] = Bb[(size_t)(kg*8+i)*128 + j];
        uint4 pk;
        pk.x = (unsigned int)v[0] | ((unsigned int)v[1]<<16);
        pk.y = (unsigned int)v[2] | ((unsigned int)v[3]<<16);
        pk.z = (unsigned int)v[4] | ((unsigned int)v[5]<<16);
        pk.w = (unsigned int)v[6] | ((unsigned int)v[7]<<16);
        *reinterpret_cast<uint4*>(&Bs[j*136 + kg*8]) = pk;
    }
    __syncthreads();

    f32x4 acc[2][8];
    #pragma unroll
    for(int rt=0;rt<2;rt++)
        #pragma unroll
        for(int ct=0;ct<8;ct++) acc[rt][ct] = (f32x4){0.f,0.f,0.f,0.f};

    #pragma unroll
    for(int kk=0;kk<4;kk++){
        #pragma unroll
        for(int ct=0;ct<8;ct++){
            bf16x8 bfr = *reinterpret_cast<const bf16x8*>(&Bs[(ct*16+lr)*136 + kk*32 + lg*8]);
            acc[0][ct] = __builtin_amdgcn_mfma_f32_16x16x32_bf16(af[kk][0], bfr, acc[0][ct], 0,0,0);
            acc[1][ct] = __builtin_amdgcn_mfma_f32_16x16x32_bf16(af[kk][1], bfr, acc[1][ct], 0,0,0);
        }
    }
    #pragma unroll
    for(int rt=0;rt<2;rt++){
        #pragma unroll
        for(int ct=0;ct<8;ct++){
            #pragma unroll
            for(int r=0;r<4;r++){
                int row = w*32 + rt*16 + lg*4 + r;
                int col = ct*16 + lr;
                float v = acc[rt][ct][r] * ms[row*128 + col];
                Pb[(size_t)row*128 + col] = f2bf(v);
            }
        }
    }
}

// ---------------------------------------------------------------- head
__global__ __launch_bounds__(1024) void k_head(
    const float* __restrict__ xo, const float* __restrict__ h1w, const float* __restrict__ h1b,
    const float* __restrict__ h2w, const float* __restrict__ h2b, float* __restrict__ out)
{
    __shared__ float hbuf[NBATCH][32];
    const int t = threadIdx.x;
    const int b = t >> 5, j = t & 31;
    float a = h1b[j];
    #pragma unroll 8
    for(int k=0;k<384;k++) a += xo[b*384+k]*h1w[j*384+k];
    a = a > 0.f ? a : 0.f;
    hbuf[b][j] = a;
    __syncthreads();
    if(j == 0){
        float s = h2b[0];
        #pragma unroll
        for(int k=0;k<32;k++) s += hbuf[b][k]*h2w[k];
        out[b] = s;
    }
}

// ----------------------------------------------------------------
extern "C" void kernel_launch(void* const* d_in, const int* in_sizes, int n_in,
                              void* d_out, int out_size, void* d_ws, size_t ws_size,
                              hipStream_t stream)
{
    (void)in_sizes; (void)n_in; (void)out_size;
    const float* X2  = (const float*)d_in[0];
    const float* M   = (const float*)d_in[1];
    const float* w11 = (const float*)d_in[2];  const float* b11 = (const float*)d_in[3];
    const float* w12 = (const float*)d_in[4];  const float* b12 = (const float*)d_in[5];
    const float* w13 = (const float*)d_in[6];  const float* b13 = (const float*)d_in[7];
    const float* w21 = (const float*)d_in[8];  const float* b21 = (const float*)d_in[9];
    const float* w22 = (const float*)d_in[10]; const float* b22 = (const float*)d_in[11];
    const float* w23 = (const float*)d_in[12]; const float* b23 = (const float*)d_in[13];
    const float* w31 = (const float*)d_in[14]; const float* b31 = (const float*)d_in[15];
    const float* w32 = (const float*)d_in[16]; const float* b32 = (const float*)d_in[17];
    const float* w33 = (const float*)d_in[18]; const float* b33 = (const float*)d_in[19];
    const float* h1w = (const float*)d_in[20]; const float* h1b = (const float*)d_in[21];
    const float* h2w = (const float*)d_in[22]; const float* h2b = (const float*)d_in[23];
    float* out = (float*)d_out;

    char* ws = (char*)d_ws;
    size_t off = 0;
    float* msum = (float*)(ws + off); off += (size_t)NBATCH*HW*4;            // 2 MB
    float* xo   = (float*)(ws + off); off += (size_t)NBATCH*384*4;           // 48 KB
    unsigned short* wp  = (unsigned short*)(ws + off); off += (size_t)WPREP_TOTAL*2; // 624 KB
    off = (off + 255) & ~(size_t)255;
    unsigned short* X2b = (unsigned short*)(ws + off); off += (size_t)NBATCH*64*8192*2; // 32 MB
    off = (off + 255) & ~(size_t)255;

    int bc = 32;
    while (bc > 1 && off + 4ull*(size_t)bc*CCH*HW*2 > ws_size) bc >>= 1;
    size_t bufb = (size_t)bc*CCH*HW*2;
    unsigned short* bufA = (unsigned short*)(ws + off);            // plain; P in-place
    unsigned short* bufB = (unsigned short*)(ws + off + bufb);     // plain
    unsigned short* Xs1  = (unsigned short*)(ws + off + 2*bufb);   // swz block1 out
    unsigned short* Xs2  = (unsigned short*)(ws + off + 3*bufb);   // swz block2 out

    const unsigned short* Wab1 = wp + 0;       // z stride 8192
    const unsigned short* Wc1  = wp + 16384;
    const unsigned short* Wab2 = wp + 57344;   // z stride 32768
    const unsigned short* Wc2  = wp + 122880;
    const unsigned short* Wab3 = wp + 188416;  // z stride 32768
    const unsigned short* Wc3  = wp + 253952;

    k_prep<<<(WPREP_TOTAL+255)/256, 256, 0, stream>>>(w11,w12,w13,w21,w22,w23,w31,w32,w33, wp);
    k_xprep<<<dim3(64, NBATCH), 256, 0, stream>>>(X2, X2b);
    k_msum<<<(NBATCH*HW)/256, 256, 0, stream>>>(M, msum);
    hipMemsetAsync(xo, 0, (size_t)NBATCH*384*4, stream);

    for(int b0 = 0; b0 < NBATCH; b0 += bc){
        dim3 gab(64, bc, 2);
        dim3 gcc(64, bc, 1);
        dim3 gmat(bc*CCH);
        // ---- block 1
        k_conv<0,1,false,true ,true ><<<gab, 512, 0, stream>>>(Wab1, bufA, X2b, b11, b12, msum, M, bufA, bufB, xo, b0, 0);
        k_bmm<<<gmat, 256, 0, stream>>>(bufA, bufB, msum, bufA, b0);
        k_conv<4,1,true ,true ,true ><<<gcc, 512, 0, stream>>>(Wc1, bufA, X2b, b13, b13, msum, M, Xs1, nullptr, xo, b0, 0);
        // ---- block 2
        k_conv<0,4,false,false,true ><<<gab, 512, 0, stream>>>(Wab2, bufA, Xs1, b21, b22, msum, M, bufA, bufB, xo, b0, 0);
        k_bmm<<<gmat, 256, 0, stream>>>(bufA, bufB, msum, bufA, b0);
        k_conv<4,4,true ,false,true ><<<gcc, 512, 0, stream>>>(Wc2, bufA, Xs1, b23, b23, msum, M, Xs2, nullptr, xo, b0, 128);
        // ---- block 3
        k_conv<0,4,false,false,true ><<<gab, 512, 0, stream>>>(Wab3, bufA, Xs2, b31, b32, msum, M, bufA, bufB, xo, b0, 0);
        k_bmm<<<gmat, 256, 0, stream>>>(bufA, bufB, msum, bufA, b0);
        k_conv<4,4,true ,false,false><<<gcc, 512, 0, stream>>>(Wc3, bufA, Xs2, b33, b33, msum, M, bufB, nullptr, xo, b0, 256);
    }
    k_head<<<1, 1024, 0, stream>>>(xo, h1w, h1b, h2w, h2b, out);
}

// Round 7
// 1540.439 us; speedup vs baseline: 1.0329x; 1.0329x over previous
//
#include <hip/hip_runtime.h>
#include <stdint.h>
#include <stddef.h>

#define NBATCH 32
#define HW     16384      // 128*128
#define CCH    128

typedef short bf16x8 __attribute__((ext_vector_type(8)));
typedef float f32x4  __attribute__((ext_vector_type(4)));

__device__ __forceinline__ float bf2f(unsigned short u){
    union { unsigned int i; float f; } v; v.i = ((unsigned int)u) << 16; return v.f;
}
__device__ __forceinline__ unsigned short f2bf(float f){
    union { float f; unsigned int i; } v; v.f = f;
    unsigned int x = v.i;
    x += 0x7fffu + ((x >> 16) & 1u);   // round-to-nearest-even
    return (unsigned short)(x >> 16);
}
__device__ __forceinline__ unsigned int h16(uint2 u, int j){
    unsigned int v = (j & 2) ? u.y : u.x;
    return (j & 1) ? (v >> 16) : (v & 0xffffu);
}
__device__ __forceinline__ void gl_lds16(const unsigned short* g, unsigned short* l){
    __builtin_amdgcn_global_load_lds(
        reinterpret_cast<const __attribute__((address_space(1))) unsigned int*>(
            reinterpret_cast<uintptr_t>(g)),
        reinterpret_cast<__attribute__((address_space(3))) unsigned int*>(
            reinterpret_cast<uintptr_t>(l)),
        16, 0, 0);
}
template<int N> __device__ __forceinline__ void vmwait(){
    asm volatile("s_waitcnt vmcnt(%0)" :: "n"(N) : "memory");
}

// ---------------------------------------------------------------- weight prep:
// per conv: [NCH][2(hi/lo)][128][32] bf16, K-swizzled: stored col cs holds logical
// c = ((cs>>3)^((row>>1)&3))*8 + (cs&7). Chunks of 8192 shorts (16 KB).
// segments (shorts): wa1@0(1) wb1@8192(1) wc1@16384(5) wa2@57344(4) wb2@90112(4)
// wc2@122880(8) wa3@188416(4) wb3@221184(4) wc3@253952(8). total 319488.
#define WPREP_TOTAL 319488
__global__ __launch_bounds__(256) void k_prep(
    const float* __restrict__ w11, const float* __restrict__ w12, const float* __restrict__ w13,
    const float* __restrict__ w21, const float* __restrict__ w22, const float* __restrict__ w23,
    const float* __restrict__ w31, const float* __restrict__ w32, const float* __restrict__ w33,
    unsigned short* __restrict__ wp)
{
    int i = blockIdx.x*256 + threadIdx.x;
    if(i >= WPREP_TOTAL) return;
    const float* src; int K, mode, base;   // mode: 0=normal 1=dup16 2=wc1
    if     (i < 8192)  { src=w11; K=16;  mode=1; base=0;      }
    else if(i < 16384) { src=w12; K=16;  mode=1; base=8192;   }
    else if(i < 57344) { src=w13; K=144; mode=2; base=16384;  }
    else if(i < 90112) { src=w21; K=128; mode=0; base=57344;  }
    else if(i < 122880){ src=w22; K=128; mode=0; base=90112;  }
    else if(i < 188416){ src=w23; K=256; mode=0; base=122880; }
    else if(i < 221184){ src=w31; K=128; mode=0; base=188416; }
    else if(i < 253952){ src=w32; K=128; mode=0; base=221184; }
    else               { src=w33; K=256; mode=0; base=253952; }
    int j  = i - base;
    int ck = j >> 13;
    int jj = j & 8191;
    int half = jj >> 12;
    int row  = (jj >> 5) & 127;
    int cs   = jj & 31;
    int s    = (row >> 1) & 3;
    int c    = (((cs >> 3) ^ s) << 3) | (cs & 7);   // logical k within chunk
    int col  = (mode==1) ? (c & 15)
             : (mode==2) ? (ck < 4 ? ck*32 + c : 128 + (c & 15))
             :             ck*32 + c;
    float v = src[row*K + col];
    unsigned short hi = f2bf(v);
    wp[i] = half ? f2bf(v - bf2f(hi)) : hi;
}

// ---------------------------------------------------------------- X2 -> swizzled hw-major hi/lo:
// X2b[b][ht(64)][256 hwin][32 c] bf16; c 0-15 = hi, 16-31 = lo; K-swizzled like W.
__global__ __launch_bounds__(256) void k_xprep(const float* __restrict__ X2, unsigned short* __restrict__ X2b){
    const int ht = blockIdx.x, b = blockIdx.y, t = threadIdx.x;
    const float* src = X2 + (size_t)b*16*HW + ht*256 + t;
    unsigned short hv[16], lv[16];
    #pragma unroll
    for(int c=0;c<16;c++){
        float v = src[(size_t)c*HW];
        hv[c] = f2bf(v);
        lv[c] = f2bf(v - bf2f(hv[c]));
    }
    const int s = (t >> 1) & 3;
    unsigned short* dst = X2b + ((size_t)b*64 + ht)*8192 + t*32;
    #pragma unroll
    for(int g=0; g<4; g++){
        const unsigned short* q = (g < 2) ? &hv[(g&1)*8] : &lv[(g&1)*8];
        uint4 pk;
        pk.x = (unsigned int)q[0] | ((unsigned int)q[1]<<16);
        pk.y = (unsigned int)q[2] | ((unsigned int)q[3]<<16);
        pk.z = (unsigned int)q[4] | ((unsigned int)q[5]<<16);
        pk.w = (unsigned int)q[6] | ((unsigned int)q[7]<<16);
        *reinterpret_cast<uint4*>(dst + ((g ^ s) << 3)) = pk;
    }
}

// ---------------------------------------------------------------- Msum = M[:,0]+M[:,1]
__global__ __launch_bounds__(256) void k_msum(const float* __restrict__ M, float* __restrict__ msum){
    int i = blockIdx.x*256 + threadIdx.x;
    int b = i >> 14, hw = i & (HW-1);
    msum[i] = M[(size_t)b*2*HW + hw] + M[(size_t)b*2*HW + HW + hw];
}

// ---------------------------------------------------------------- unified conv GEMM (512 thr, 8 waves 2x4)
// Out[128 ch][256 hw-tile] = relu((W @ concat(P, X) + bias) * Msum).
// 1 barrier/chunk; W dbuf (1-ahead DMA), X tbuf (2-ahead DMA), P reg (1-ahead).
template<int NCHP, int NCHX, bool CC, bool GX, bool STORE>
__global__ __launch_bounds__(512,4) void k_conv(
    const unsigned short* __restrict__ Wp,
    const unsigned short* __restrict__ Psrc,   // plain [bi][128][HW]
    const unsigned short* __restrict__ Xsrc,   // swz [b][ht][NCHX][8192]
    const float* __restrict__ biasA, const float* __restrict__ biasB,
    const float* __restrict__ msum, const float* __restrict__ Mfull,
    unsigned short* __restrict__ OutA, unsigned short* __restrict__ OutB,
    float* __restrict__ xo, int b0, int xo_off)
{
    constexpr int NCH = NCHP + NCHX;
    __shared__ unsigned short Wl[2*8192];   // 32 KB, double-buffered
    __shared__ unsigned short Xl[3*8192];   // 48 KB, triple-buffered
    const int bi = blockIdx.y, bg = b0 + bi;
    const int ht = CC ? blockIdx.x : (blockIdx.x >> 1);
    const int z  = CC ? 0 : (blockIdx.x & 1);
    const int t = threadIdx.x;
    const int w = t >> 6, lane = t & 63;
    const int lr = lane & 15, lg = lane >> 4;
    const int wm = w & 1, wn = w >> 1;           // rows wm*64.., cols wn*64..
    const int cg = t & 7, h4 = t >> 3;           // P staging mapping
    const unsigned short* Wseg  = Wp + (size_t)z*NCH*8192;
    const unsigned short* pbase = Psrc + (size_t)bi*CCH*HW;
    const unsigned short* xbase = Xsrc + ((size_t)(GX ? bg : bi)*64 + ht)*NCHX*8192;

    f32x4 acc[4][4];
    #pragma unroll
    for(int mf=0; mf<4; mf++)
        #pragma unroll
        for(int nf=0; nf<4; nf++) acc[mf][nf] = (f32x4){0.f,0.f,0.f,0.f};

    uint2 pr[4];

    auto stageW = [&](int ck){
        const unsigned short* s = Wseg + (size_t)ck*8192 + t*8;
        unsigned short* d = &Wl[(ck&1)*8192 + t*8];
        gl_lds16(s, d); gl_lds16(s + 4096, d + 4096);
    };
    auto stageX = [&](int ck){                    // ck absolute; X chunk = ck-NCHP
        const unsigned short* s = xbase + (size_t)(ck - NCHP)*8192 + t*8;
        unsigned short* d = &Xl[(ck%3)*8192 + t*8];
        gl_lds16(s, d); gl_lds16(s + 4096, d + 4096);
    };
    auto loadP = [&](int ck){
        const unsigned short* s = pbase + (size_t)(ck*32 + cg*4)*HW + ht*256 + h4*4;
        #pragma unroll
        for(int i2=0;i2<4;i2++) pr[i2] = *reinterpret_cast<const uint2*>(s + (size_t)i2*HW);
    };
    auto writeP = [&](int xb){
        #pragma unroll
        for(int j=0;j<4;j++){
            int hwin = h4*4 + j;
            int sx = (hwin >> 1) & 3;
            int pos = (((cg>>1) ^ sx) << 3) + (cg&1)*4;
            uint2 v;
            v.x = h16(pr[0],j) | (h16(pr[1],j) << 16);
            v.y = h16(pr[2],j) | (h16(pr[3],j) << 16);
            *reinterpret_cast<uint2*>(&Xl[xb*8192 + hwin*32 + pos]) = v;
        }
    };
    auto compute = [&](int wb, int xb){
        const unsigned short* Wb = &Wl[wb*8192];
        const unsigned short* Xb = &Xl[xb*8192];
        #pragma unroll
        for(int hp=0; hp<2; hp++){
            bf16x8 ah[2], al[2];
            #pragma unroll
            for(int m2=0;m2<2;m2++){
                int row = wm*64 + (hp*2+m2)*16 + lr;
                int off = row*32 + ((lg ^ ((row>>1)&3)) << 3);
                ah[m2] = *reinterpret_cast<const bf16x8*>(&Wb[off]);
                al[m2] = *reinterpret_cast<const bf16x8*>(&Wb[4096 + off]);
            }
            #pragma unroll
            for(int nf=0;nf<4;nf++){
                int hwin = wn*64 + nf*16 + lr;
                bf16x8 bfr = *reinterpret_cast<const bf16x8*>(&Xb[hwin*32 + ((lg ^ ((hwin>>1)&3)) << 3)]);
                #pragma unroll
                for(int m2=0;m2<2;m2++){
                    acc[hp*2+m2][nf] = __builtin_amdgcn_mfma_f32_16x16x32_bf16(ah[m2], bfr, acc[hp*2+m2][nf], 0,0,0);
                    acc[hp*2+m2][nf] = __builtin_amdgcn_mfma_f32_16x16x32_bf16(al[m2], bfr, acc[hp*2+m2][nf], 0,0,0);
                }
            }
        }
    };

    // prologue (issue order: W0, P0/X0, X1)
    stageW(0);
    if constexpr (NCHP > 0) loadP(0); else stageX(0);
    if constexpr (NCH > 1 && NCHP <= 1) stageX(1);

    // one barrier per chunk; counted vmcnt: keep X(I+1) (issued last iter) in flight.
#define STEP(I) \
    if constexpr ((I) < NCH) { \
        constexpr int NWT = (((I)+1 < NCH) && ((I)+1 >= NCHP)) ? 2 : 0; \
        vmwait<NWT>(); \
        __builtin_amdgcn_sched_barrier(0); \
        if constexpr ((I) < NCHP) { \
            writeP((I)%3); \
            asm volatile("s_waitcnt lgkmcnt(0)" ::: "memory"); \
            __builtin_amdgcn_sched_barrier(0); \
        } \
        __builtin_amdgcn_s_barrier(); \
        if constexpr ((I)+1 < NCH) stageW((I)+1); \
        if constexpr (((I)+1 < NCH) && ((I)+1 < NCHP)) loadP((I)+1); \
        if constexpr (((I)+2 < NCH) && ((I)+2 >= NCHP)) stageX((I)+2); \
        __builtin_amdgcn_s_setprio(1); \
        compute((I)%2, (I)%3); \
        __builtin_amdgcn_s_setprio(0); \
    }
    STEP(0) STEP(1) STEP(2) STEP(3) STEP(4) STEP(5) STEP(6) STEP(7)
#undef STEP

    // ---- epilogue
    float msv[4], mdv[4];
    #pragma unroll
    for(int nf=0; nf<4; nf++){
        int hwi = ht*256 + wn*64 + nf*16 + lr;
        msv[nf] = msum[(size_t)bg*HW + hwi];
        if constexpr (CC) mdv[nf] = Mfull[(size_t)bg*2*HW + hwi];
    }
    if constexpr (!CC){
        const float* bias = z ? biasB : biasA;
        unsigned short* dst = (z ? OutB : OutA) + (size_t)bi*CCH*HW;
        #pragma unroll
        for(int mf=0; mf<4; mf++){
            #pragma unroll
            for(int reg=0; reg<4; reg++){
                int row = wm*64 + mf*16 + lg*4 + reg;
                float bv = bias[row];
                #pragma unroll
                for(int nf=0; nf<4; nf++){
                    float v2 = (acc[mf][nf][reg] + bv) * msv[nf];
                    v2 = v2 > 0.f ? v2 : 0.f;
                    dst[(size_t)row*HW + ht*256 + wn*64 + nf*16 + lr] = f2bf(v2);
                }
            }
        }
    } else {
        #pragma unroll
        for(int mf=0; mf<4; mf++){
            const int ckO = wm*2 + (mf>>1);
            const int c0  = (mf&1)*16 + lg*4;        // ch within 32-chunk
            float red[4] = {0.f,0.f,0.f,0.f};
            #pragma unroll
            for(int nf=0; nf<4; nf++){
                int hwin = wn*64 + nf*16 + lr;
                float vv[4];
                #pragma unroll
                for(int reg=0; reg<4; reg++){
                    int row = wm*64 + mf*16 + lg*4 + reg;
                    float v2 = (acc[mf][nf][reg] + biasA[row]) * msv[nf];
                    v2 = v2 > 0.f ? v2 : 0.f;
                    vv[reg] = v2;
                    red[reg] += v2 * mdv[nf];
                }
                if constexpr (STORE){
                    int sx = (hwin>>1)&3;
                    int pos = ((((c0>>3) ^ sx) << 3)) + (c0 & 7);
                    uint2 pk;
                    pk.x = (unsigned int)f2bf(vv[0]) | ((unsigned int)f2bf(vv[1])<<16);
                    pk.y = (unsigned int)f2bf(vv[2]) | ((unsigned int)f2bf(vv[3])<<16);
                    *reinterpret_cast<uint2*>(OutA + (((size_t)bi*64 + ht)*4 + ckO)*8192 + hwin*32 + pos) = pk;
                }
            }
            #pragma unroll
            for(int reg=0; reg<4; reg++){
                float r = red[reg];
                r += __shfl_xor(r, 1);
                r += __shfl_xor(r, 2);
                r += __shfl_xor(r, 4);
                r += __shfl_xor(r, 8);
                if(lr == 0)
                    atomicAdd(&xo[(size_t)bg*384 + xo_off + wm*64 + mf*16 + lg*4 + reg], r);
            }
        }
    }
}

// ---------------------------------------------------------------- batched spatial matmul:
// P[b,c] = (A[b,c] @ B[b,c]) * Msum[b]  (128x128x128 bf16 MFMA; P aliases A)
__global__ __launch_bounds__(256) void k_bmm(
    const unsigned short* __restrict__ A, const unsigned short* __restrict__ Bm,
    const float* __restrict__ msum, unsigned short* __restrict__ P, int b0)
{
    __shared__ unsigned short Bs[128*136];
    const int m  = blockIdx.x;
    const int bi = m >> 7;
    const int bg = b0 + bi;
    const unsigned short* Ab = A  + (size_t)m*HW;
    const unsigned short* Bb = Bm + (size_t)m*HW;
    unsigned short*       Pb = P  + (size_t)m*HW;
    const float* ms = msum + (size_t)bg*HW;
    const int t = threadIdx.x;
    const int w  = t >> 6;
    const int l  = t & 63;
    const int lr = l & 15;
    const int lg = l >> 4;

    bf16x8 af[4][2];
    #pragma unroll
    for(int kk=0;kk<4;kk++)
        #pragma unroll
        for(int rt=0;rt<2;rt++)
            af[kk][rt] = *reinterpret_cast<const bf16x8*>(Ab + (size_t)(w*32 + rt*16 + lr)*128 + kk*32 + lg*8);

    #pragma unroll
    for(int it=0; it<8; it++){
        int task = it*256 + t;
        int j  = task & 127;
        int kg = task >> 7;
        unsigned short v[8];
        #pragma unroll
        for(int i=0;i<8;i++) v[i] = Bb[(size_t)(kg*8+i)*128 + j];
        uint4 pk;
        pk.x = (unsigned int)v[0] | ((unsigned int)v[1]<<16);
        pk.y = (unsigned int)v[2] | ((unsigned int)v[3]<<16);
        pk.z = (unsigned int)v[4] | ((unsigned int)v[5]<<16);
        pk.w = (unsigned int)v[6] | ((unsigned int)v[7]<<16);
        *reinterpret_cast<uint4*>(&Bs[j*136 + kg*8]) = pk;
    }
    __syncthreads();

    f32x4 acc[2][8];
    #pragma unroll
    for(int rt=0;rt<2;rt++)
        #pragma unroll
        for(int ct=0;ct<8;ct++) acc[rt][ct] = (f32x4){0.f,0.f,0.f,0.f};

    #pragma unroll
    for(int kk=0;kk<4;kk++){
        #pragma unroll
        for(int ct=0;ct<8;ct++){
            bf16x8 bfr = *reinterpret_cast<const bf16x8*>(&Bs[(ct*16+lr)*136 + kk*32 + lg*8]);
            acc[0][ct] = __builtin_amdgcn_mfma_f32_16x16x32_bf16(af[kk][0], bfr, acc[0][ct], 0,0,0);
            acc[1][ct] = __builtin_amdgcn_mfma_f32_16x16x32_bf16(af[kk][1], bfr, acc[1][ct], 0,0,0);
        }
    }
    #pragma unroll
    for(int rt=0;rt<2;rt++){
        #pragma unroll
        for(int ct=0;ct<8;ct++){
            #pragma unroll
            for(int r=0;r<4;r++){
                int row = w*32 + rt*16 + lg*4 + r;
                int col = ct*16 + lr;
                float v = acc[rt][ct][r] * ms[row*128 + col];
                Pb[(size_t)row*128 + col] = f2bf(v);
            }
        }
    }
}

// ---------------------------------------------------------------- head
__global__ __launch_bounds__(1024) void k_head(
    const float* __restrict__ xo, const float* __restrict__ h1w, const float* __restrict__ h1b,
    const float* __restrict__ h2w, const float* __restrict__ h2b, float* __restrict__ out)
{
    __shared__ float hbuf[NBATCH][32];
    const int t = threadIdx.x;
    const int b = t >> 5, j = t & 31;
    float a = h1b[j];
    #pragma unroll 8
    for(int k=0;k<384;k++) a += xo[b*384+k]*h1w[j*384+k];
    a = a > 0.f ? a : 0.f;
    hbuf[b][j] = a;
    __syncthreads();
    if(j == 0){
        float s = h2b[0];
        #pragma unroll
        for(int k=0;k<32;k++) s += hbuf[b][k]*h2w[k];
        out[b] = s;
    }
}

// ----------------------------------------------------------------
extern "C" void kernel_launch(void* const* d_in, const int* in_sizes, int n_in,
                              void* d_out, int out_size, void* d_ws, size_t ws_size,
                              hipStream_t stream)
{
    (void)in_sizes; (void)n_in; (void)out_size;
    const float* X2  = (const float*)d_in[0];
    const float* M   = (const float*)d_in[1];
    const float* w11 = (const float*)d_in[2];  const float* b11 = (const float*)d_in[3];
    const float* w12 = (const float*)d_in[4];  const float* b12 = (const float*)d_in[5];
    const float* w13 = (const float*)d_in[6];  const float* b13 = (const float*)d_in[7];
    const float* w21 = (const float*)d_in[8];  const float* b21 = (const float*)d_in[9];
    const float* w22 = (const float*)d_in[10]; const float* b22 = (const float*)d_in[11];
    const float* w23 = (const float*)d_in[12]; const float* b23 = (const float*)d_in[13];
    const float* w31 = (const float*)d_in[14]; const float* b31 = (const float*)d_in[15];
    const float* w32 = (const float*)d_in[16]; const float* b32 = (const float*)d_in[17];
    const float* w33 = (const float*)d_in[18]; const float* b33 = (const float*)d_in[19];
    const float* h1w = (const float*)d_in[20]; const float* h1b = (const float*)d_in[21];
    const float* h2w = (const float*)d_in[22]; const float* h2b = (const float*)d_in[23];
    float* out = (float*)d_out;

    char* ws = (char*)d_ws;
    size_t off = 0;
    float* msum = (float*)(ws + off); off += (size_t)NBATCH*HW*4;            // 2 MB
    float* xo   = (float*)(ws + off); off += (size_t)NBATCH*384*4;           // 48 KB
    unsigned short* wp  = (unsigned short*)(ws + off); off += (size_t)WPREP_TOTAL*2; // 624 KB
    off = (off + 255) & ~(size_t)255;
    unsigned short* X2b = (unsigned short*)(ws + off); off += (size_t)NBATCH*64*8192*2; // 32 MB
    off = (off + 255) & ~(size_t)255;

    int bc = 32;
    while (bc > 1 && off + 4ull*(size_t)bc*CCH*HW*2 > ws_size) bc >>= 1;
    size_t bufb = (size_t)bc*CCH*HW*2;
    unsigned short* bufA = (unsigned short*)(ws + off);            // plain; P in-place
    unsigned short* bufB = (unsigned short*)(ws + off + bufb);     // plain
    unsigned short* Xs1  = (unsigned short*)(ws + off + 2*bufb);   // swz block1 out
    unsigned short* Xs2  = (unsigned short*)(ws + off + 3*bufb);   // swz block2 out

    const unsigned short* Wab1 = wp + 0;       // z stride 8192
    const unsigned short* Wc1  = wp + 16384;
    const unsigned short* Wab2 = wp + 57344;   // z stride 32768
    const unsigned short* Wc2  = wp + 122880;
    const unsigned short* Wab3 = wp + 188416;  // z stride 32768
    const unsigned short* Wc3  = wp + 253952;

    k_prep<<<(WPREP_TOTAL+255)/256, 256, 0, stream>>>(w11,w12,w13,w21,w22,w23,w31,w32,w33, wp);
    k_xprep<<<dim3(64, NBATCH), 256, 0, stream>>>(X2, X2b);
    k_msum<<<(NBATCH*HW)/256, 256, 0, stream>>>(M, msum);
    hipMemsetAsync(xo, 0, (size_t)NBATCH*384*4, stream);

    for(int b0 = 0; b0 < NBATCH; b0 += bc){
        dim3 gab(128, bc);     // z folded into x: adjacent blocks share X tile (L2)
        dim3 gcc(64, bc);
        dim3 gmat(bc*CCH);
        // ---- block 1
        k_conv<0,1,false,true ,true ><<<gab, 512, 0, stream>>>(Wab1, bufA, X2b, b11, b12, msum, M, bufA, bufB, xo, b0, 0);
        k_bmm<<<gmat, 256, 0, stream>>>(bufA, bufB, msum, bufA, b0);
        k_conv<4,1,true ,true ,true ><<<gcc, 512, 0, stream>>>(Wc1, bufA, X2b, b13, b13, msum, M, Xs1, nullptr, xo, b0, 0);
        // ---- block 2
        k_conv<0,4,false,false,true ><<<gab, 512, 0, stream>>>(Wab2, bufA, Xs1, b21, b22, msum, M, bufA, bufB, xo, b0, 0);
        k_bmm<<<gmat, 256, 0, stream>>>(bufA, bufB, msum, bufA, b0);
        k_conv<4,4,true ,false,true ><<<gcc, 512, 0, stream>>>(Wc2, bufA, Xs1, b23, b23, msum, M, Xs2, nullptr, xo, b0, 128);
        // ---- block 3
        k_conv<0,4,false,false,true ><<<gab, 512, 0, stream>>>(Wab3, bufA, Xs2, b31, b32, msum, M, bufA, bufB, xo, b0, 0);
        k_bmm<<<gmat, 256, 0, stream>>>(bufA, bufB, msum, bufA, b0);
        k_conv<4,4,true ,false,false><<<gcc, 512, 0, stream>>>(Wc3, bufA, Xs2, b33, b33, msum, M, bufB, nullptr, xo, b0, 256);
    }
    k_head<<<1, 1024, 0, stream>>>(xo, h1w, h1b, h2w, h2b, out);
}

// Round 8
// 1291.802 us; speedup vs baseline: 1.2317x; 1.1925x over previous
//
#include <hip/hip_runtime.h>
#include <stdint.h>
#include <stddef.h>

#define NBATCH 32
#define HW     16384      // 128*128
#define CCH    128

typedef short bf16x8 __attribute__((ext_vector_type(8)));
typedef float f32x4  __attribute__((ext_vector_type(4)));

__device__ __forceinline__ float bf2f(unsigned short u){
    union { unsigned int i; float f; } v; v.i = ((unsigned int)u) << 16; return v.f;
}
__device__ __forceinline__ unsigned short f2bf(float f){
    union { float f; unsigned int i; } v; v.f = f;
    unsigned int x = v.i;
    x += 0x7fffu + ((x >> 16) & 1u);   // round-to-nearest-even
    return (unsigned short)(x >> 16);
}
__device__ __forceinline__ unsigned int h16(uint2 u, int j){
    unsigned int v = (j & 2) ? u.y : u.x;
    return (j & 1) ? (v >> 16) : (v & 0xffffu);
}
__device__ __forceinline__ void gl_lds16(const unsigned short* g, unsigned short* l){
    __builtin_amdgcn_global_load_lds(
        reinterpret_cast<const __attribute__((address_space(1))) unsigned int*>(
            reinterpret_cast<uintptr_t>(g)),
        reinterpret_cast<__attribute__((address_space(3))) unsigned int*>(
            reinterpret_cast<uintptr_t>(l)),
        16, 0, 0);
}
template<int N> __device__ __forceinline__ void vmwait(){
    asm volatile("s_waitcnt vmcnt(%0)" :: "n"(N) : "memory");
}

// ---------------------------------------------------------------- weight prep:
// per conv: [NCH][2(hi/lo)][128][32] bf16, K-swizzled: stored col cs holds logical
// c = ((cs>>3)^((row>>1)&3))*8 + (cs&7). Chunks of 8192 shorts (16 KB).
// segments (shorts): wa1@0(1) wb1@8192(1) wc1@16384(5) wa2@57344(4) wb2@90112(4)
// wc2@122880(8) wa3@188416(4) wb3@221184(4) wc3@253952(8). total 319488.
#define WPREP_TOTAL 319488
__global__ __launch_bounds__(256) void k_prep(
    const float* __restrict__ w11, const float* __restrict__ w12, const float* __restrict__ w13,
    const float* __restrict__ w21, const float* __restrict__ w22, const float* __restrict__ w23,
    const float* __restrict__ w31, const float* __restrict__ w32, const float* __restrict__ w33,
    unsigned short* __restrict__ wp)
{
    int i = blockIdx.x*256 + threadIdx.x;
    if(i >= WPREP_TOTAL) return;
    const float* src; int K, mode, base;   // mode: 0=normal 1=dup16 2=wc1
    if     (i < 8192)  { src=w11; K=16;  mode=1; base=0;      }
    else if(i < 16384) { src=w12; K=16;  mode=1; base=8192;   }
    else if(i < 57344) { src=w13; K=144; mode=2; base=16384;  }
    else if(i < 90112) { src=w21; K=128; mode=0; base=57344;  }
    else if(i < 122880){ src=w22; K=128; mode=0; base=90112;  }
    else if(i < 188416){ src=w23; K=256; mode=0; base=122880; }
    else if(i < 221184){ src=w31; K=128; mode=0; base=188416; }
    else if(i < 253952){ src=w32; K=128; mode=0; base=221184; }
    else               { src=w33; K=256; mode=0; base=253952; }
    int j  = i - base;
    int ck = j >> 13;
    int jj = j & 8191;
    int half = jj >> 12;
    int row  = (jj >> 5) & 127;
    int cs   = jj & 31;
    int s    = (row >> 1) & 3;
    int c    = (((cs >> 3) ^ s) << 3) | (cs & 7);   // logical k within chunk
    int col  = (mode==1) ? (c & 15)
             : (mode==2) ? (ck < 4 ? ck*32 + c : 128 + (c & 15))
             :             ck*32 + c;
    float v = src[row*K + col];
    unsigned short hi = f2bf(v);
    wp[i] = half ? f2bf(v - bf2f(hi)) : hi;
}

// ---------------------------------------------------------------- X2 -> swizzled hw-major hi/lo:
// X2b[b][ht(64)][256 hwin][32 c] bf16; c 0-15 = hi, 16-31 = lo; K-swizzled like W.
__global__ __launch_bounds__(256) void k_xprep(const float* __restrict__ X2, unsigned short* __restrict__ X2b){
    const int ht = blockIdx.x, b = blockIdx.y, t = threadIdx.x;
    const float* src = X2 + (size_t)b*16*HW + ht*256 + t;
    unsigned short hv[16], lv[16];
    #pragma unroll
    for(int c=0;c<16;c++){
        float v = src[(size_t)c*HW];
        hv[c] = f2bf(v);
        lv[c] = f2bf(v - bf2f(hv[c]));
    }
    const int s = (t >> 1) & 3;
    unsigned short* dst = X2b + ((size_t)b*64 + ht)*8192 + t*32;
    #pragma unroll
    for(int g=0; g<4; g++){
        const unsigned short* q = (g < 2) ? &hv[(g&1)*8] : &lv[(g&1)*8];
        uint4 pk;
        pk.x = (unsigned int)q[0] | ((unsigned int)q[1]<<16);
        pk.y = (unsigned int)q[2] | ((unsigned int)q[3]<<16);
        pk.z = (unsigned int)q[4] | ((unsigned int)q[5]<<16);
        pk.w = (unsigned int)q[6] | ((unsigned int)q[7]<<16);
        *reinterpret_cast<uint4*>(dst + ((g ^ s) << 3)) = pk;
    }
}

// ---------------------------------------------------------------- Msum = M[:,0]+M[:,1]
__global__ __launch_bounds__(256) void k_msum(const float* __restrict__ M, float* __restrict__ msum){
    int i = blockIdx.x*256 + threadIdx.x;
    int b = i >> 14, hw = i & (HW-1);
    msum[i] = M[(size_t)b*2*HW + hw] + M[(size_t)b*2*HW + HW + hw];
}

// ---------------------------------------------------------------- unified conv GEMM (512 thr, 8 waves 2x4)
// Out[128 ch][256 hw-tile] = relu((W @ concat(P, X) + bias) * Msum).
// 1 barrier/chunk; W dbuf (1-ahead DMA), X tbuf (2-ahead DMA), P reg (2-ahead dual-set).
template<int NCHP, int NCHX, bool CC, bool GX, bool STORE>
__global__ __launch_bounds__(512,4) void k_conv(
    const unsigned short* __restrict__ Wp,
    const unsigned short* __restrict__ Psrc,   // plain [bi][128][HW]
    const unsigned short* __restrict__ Xsrc,   // swz [b][ht][NCHX][8192]
    const float* __restrict__ biasA, const float* __restrict__ biasB,
    const float* __restrict__ msum, const float* __restrict__ Mfull,
    unsigned short* __restrict__ OutA, unsigned short* __restrict__ OutB,
    float* __restrict__ xo, int b0, int xo_off)
{
    constexpr int NCH = NCHP + NCHX;
    __shared__ unsigned short Wl[2*8192];   // 32 KB, double-buffered
    __shared__ unsigned short Xl[3*8192];   // 48 KB, triple-buffered
    const int bi = blockIdx.y, bg = b0 + bi;
    const int ht = CC ? blockIdx.x : (blockIdx.x >> 1);
    const int z  = CC ? 0 : (blockIdx.x & 1);
    const int t = threadIdx.x;
    const int w = t >> 6, lane = t & 63;
    const int lr = lane & 15, lg = lane >> 4;
    const int wm = w & 1, wn = w >> 1;           // rows wm*64.., cols wn*64..
    const int cg = t & 7, h4 = t >> 3;           // P staging mapping
    const unsigned short* Wseg  = Wp + (size_t)z*NCH*8192;
    const unsigned short* pbase = Psrc + (size_t)bi*CCH*HW;
    const unsigned short* xbase = Xsrc + ((size_t)(GX ? bg : bi)*64 + ht)*NCHX*8192;

    f32x4 acc[4][4];
    #pragma unroll
    for(int mf=0; mf<4; mf++)
        #pragma unroll
        for(int nf=0; nf<4; nf++) acc[mf][nf] = (f32x4){0.f,0.f,0.f,0.f};

    uint2 pr0[4], pr1[4];

    auto stageW = [&](int ck){
        const unsigned short* s = Wseg + (size_t)ck*8192 + t*8;
        unsigned short* d = &Wl[(ck&1)*8192 + t*8];
        gl_lds16(s, d); gl_lds16(s + 4096, d + 4096);
    };
    auto stageX = [&](int ck){                    // ck absolute; X chunk = ck-NCHP
        const unsigned short* s = xbase + (size_t)(ck - NCHP)*8192 + t*8;
        unsigned short* d = &Xl[(ck%3)*8192 + t*8];
        gl_lds16(s, d); gl_lds16(s + 4096, d + 4096);
    };
    auto loadP = [&](int ck, uint2 (&pr)[4]){
        const unsigned short* s = pbase + (size_t)(ck*32 + cg*4)*HW + ht*256 + h4*4;
        #pragma unroll
        for(int i2=0;i2<4;i2++) pr[i2] = *reinterpret_cast<const uint2*>(s + (size_t)i2*HW);
    };
    auto writeP = [&](int xb, uint2 (&pr)[4]){
        #pragma unroll
        for(int j=0;j<4;j++){
            int hwin = h4*4 + j;
            int sx = (hwin >> 1) & 3;
            int pos = (((cg>>1) ^ sx) << 3) + (cg&1)*4;
            uint2 v;
            v.x = h16(pr[0],j) | (h16(pr[1],j) << 16);
            v.y = h16(pr[2],j) | (h16(pr[3],j) << 16);
            *reinterpret_cast<uint2*>(&Xl[xb*8192 + hwin*32 + pos]) = v;
        }
    };
    auto compute = [&](int wb, int xb){
        const unsigned short* Wb = &Wl[wb*8192];
        const unsigned short* Xb = &Xl[xb*8192];
        #pragma unroll
        for(int hp=0; hp<2; hp++){
            bf16x8 ah[2], al[2];
            #pragma unroll
            for(int m2=0;m2<2;m2++){
                int row = wm*64 + (hp*2+m2)*16 + lr;
                int off = row*32 + ((lg ^ ((row>>1)&3)) << 3);
                ah[m2] = *reinterpret_cast<const bf16x8*>(&Wb[off]);
                al[m2] = *reinterpret_cast<const bf16x8*>(&Wb[4096 + off]);
            }
            #pragma unroll
            for(int nf=0;nf<4;nf++){
                int hwin = wn*64 + nf*16 + lr;
                bf16x8 bfr = *reinterpret_cast<const bf16x8*>(&Xl[xb*8192 + hwin*32 + ((lg ^ ((hwin>>1)&3)) << 3)]);
                #pragma unroll
                for(int m2=0;m2<2;m2++){
                    acc[hp*2+m2][nf] = __builtin_amdgcn_mfma_f32_16x16x32_bf16(ah[m2], bfr, acc[hp*2+m2][nf], 0,0,0);
                    acc[hp*2+m2][nf] = __builtin_amdgcn_mfma_f32_16x16x32_bf16(al[m2], bfr, acc[hp*2+m2][nf], 0,0,0);
                }
            }
        }
        (void)Xb;
    };

    // prologue: bundle order [W0][P0|X0][P1|X1]
    stageW(0);
    if constexpr (NCHP > 0) loadP(0, pr0); else stageX(0);
    if constexpr (NCH > 1){
        if constexpr (NCHP > 1) loadP(1, pr1); else stageX(1);
    }

    // 1 barrier/chunk; counted vmcnt keeps the newest prefetch bundle in flight.
    // Issue order per STEP(I): [W(I+1)][P(I+2)|X(I+2)] -> second-slot of STEP(I-1)
    // is what survives vmwait at STEP(I): P-type=4 ops, X-type=2 ops.
#define STEP(I) \
    if constexpr ((I) < NCH) { \
        constexpr int NWT = ((I)+1 < NCHP) ? 4 : (((I)+1 < NCH) ? 2 : 0); \
        vmwait<NWT>(); \
        __builtin_amdgcn_sched_barrier(0); \
        if constexpr ((I) < NCHP) { \
            writeP((I)%3, ((I)&1) ? pr1 : pr0); \
            asm volatile("s_waitcnt lgkmcnt(0)" ::: "memory"); \
            __builtin_amdgcn_sched_barrier(0); \
        } \
        __builtin_amdgcn_s_barrier(); \
        if constexpr ((I)+1 < NCH) stageW((I)+1); \
        if constexpr ((I)+2 < NCHP) loadP((I)+2, ((I)&1) ? pr1 : pr0); \
        else if constexpr (((I)+2 >= NCHP) && ((I)+2 < NCH)) stageX((I)+2); \
        __builtin_amdgcn_s_setprio(1); \
        compute((I)%2, (I)%3); \
        __builtin_amdgcn_s_setprio(0); \
    }
    STEP(0) STEP(1) STEP(2) STEP(3) STEP(4) STEP(5) STEP(6) STEP(7)
#undef STEP

    // ---- epilogue
    float msv[4], mdv[4];
    #pragma unroll
    for(int nf=0; nf<4; nf++){
        int hwi = ht*256 + wn*64 + nf*16 + lr;
        msv[nf] = msum[(size_t)bg*HW + hwi];
        if constexpr (CC) mdv[nf] = Mfull[(size_t)bg*2*HW + hwi];
    }
    if constexpr (!CC){
        const float* bias = z ? biasB : biasA;
        unsigned short* dst = (z ? OutB : OutA) + (size_t)bi*CCH*HW;
        #pragma unroll
        for(int mf=0; mf<4; mf++){
            #pragma unroll
            for(int reg=0; reg<4; reg++){
                int row = wm*64 + mf*16 + lg*4 + reg;
                float bv = bias[row];
                #pragma unroll
                for(int nf=0; nf<4; nf++){
                    float v2 = (acc[mf][nf][reg] + bv) * msv[nf];
                    v2 = v2 > 0.f ? v2 : 0.f;
                    dst[(size_t)row*HW + ht*256 + wn*64 + nf*16 + lr] = f2bf(v2);
                }
            }
        }
    } else {
        #pragma unroll
        for(int mf=0; mf<4; mf++){
            const int ckO = wm*2 + (mf>>1);
            const int c0  = (mf&1)*16 + lg*4;        // ch within 32-chunk
            float red[4] = {0.f,0.f,0.f,0.f};
            #pragma unroll
            for(int nf=0; nf<4; nf++){
                int hwin = wn*64 + nf*16 + lr;
                float vv[4];
                #pragma unroll
                for(int reg=0; reg<4; reg++){
                    int row = wm*64 + mf*16 + lg*4 + reg;
                    float v2 = (acc[mf][nf][reg] + biasA[row]) * msv[nf];
                    v2 = v2 > 0.f ? v2 : 0.f;
                    vv[reg] = v2;
                    red[reg] += v2 * mdv[nf];
                }
                if constexpr (STORE){
                    int sx = (hwin>>1)&3;
                    int pos = ((((c0>>3) ^ sx) << 3)) + (c0 & 7);
                    uint2 pk;
                    pk.x = (unsigned int)f2bf(vv[0]) | ((unsigned int)f2bf(vv[1])<<16);
                    pk.y = (unsigned int)f2bf(vv[2]) | ((unsigned int)f2bf(vv[3])<<16);
                    *reinterpret_cast<uint2*>(OutA + (((size_t)bi*64 + ht)*4 + ckO)*8192 + hwin*32 + pos) = pk;
                }
            }
            #pragma unroll
            for(int reg=0; reg<4; reg++){
                float r = red[reg];
                r += __shfl_xor(r, 1);
                r += __shfl_xor(r, 2);
                r += __shfl_xor(r, 4);
                r += __shfl_xor(r, 8);
                if(lr == 0)
                    atomicAdd(&xo[(size_t)bg*384 + xo_off + wm*64 + mf*16 + lg*4 + reg], r);
            }
        }
    }
}

// ---------------------------------------------------------------- batched spatial matmul:
// P[b,c] = (A[b,c] @ B[b,c]) * Msum[b]  (128x128x128 bf16 MFMA; P aliases A)
__global__ __launch_bounds__(256) void k_bmm(
    const unsigned short* __restrict__ A, const unsigned short* __restrict__ Bm,
    const float* __restrict__ msum, unsigned short* __restrict__ P, int b0)
{
    __shared__ unsigned short Bs[128*136];
    const int m  = blockIdx.x;
    const int bi = m >> 7;
    const int bg = b0 + bi;
    const unsigned short* Ab = A  + (size_t)m*HW;
    const unsigned short* Bb = Bm + (size_t)m*HW;
    unsigned short*       Pb = P  + (size_t)m*HW;
    const float* ms = msum + (size_t)bg*HW;
    const int t = threadIdx.x;
    const int w  = t >> 6;
    const int l  = t & 63;
    const int lr = l & 15;
    const int lg = l >> 4;

    bf16x8 af[4][2];
    #pragma unroll
    for(int kk=0;kk<4;kk++)
        #pragma unroll
        for(int rt=0;rt<2;rt++)
            af[kk][rt] = *reinterpret_cast<const bf16x8*>(Ab + (size_t)(w*32 + rt*16 + lr)*128 + kk*32 + lg*8);

    #pragma unroll
    for(int it=0; it<8; it++){
        int task = it*256 + t;
        int j  = task & 127;
        int kg = task >> 7;
        unsigned short v[8];
        #pragma unroll
        for(int i=0;i<8;i++) v[i] = Bb[(size_t)(kg*8+i)*128 + j];
        uint4 pk;
        pk.x = (unsigned int)v[0] | ((unsigned int)v[1]<<16);
        pk.y = (unsigned int)v[2] | ((unsigned int)v[3]<<16);
        pk.z = (unsigned int)v[4] | ((unsigned int)v[5]<<16);
        pk.w = (unsigned int)v[6] | ((unsigned int)v[7]<<16);
        *reinterpret_cast<uint4*>(&Bs[j*136 + kg*8]) = pk;
    }
    __syncthreads();

    f32x4 acc[2][8];
    #pragma unroll
    for(int rt=0;rt<2;rt++)
        #pragma unroll
        for(int ct=0;ct<8;ct++) acc[rt][ct] = (f32x4){0.f,0.f,0.f,0.f};

    #pragma unroll
    for(int kk=0;kk<4;kk++){
        #pragma unroll
        for(int ct=0;ct<8;ct++){
            bf16x8 bfr = *reinterpret_cast<const bf16x8*>(&Bs[(ct*16+lr)*136 + kk*32 + lg*8]);
            acc[0][ct] = __builtin_amdgcn_mfma_f32_16x16x32_bf16(af[kk][0], bfr, acc[0][ct], 0,0,0);
            acc[1][ct] = __builtin_amdgcn_mfma_f32_16x16x32_bf16(af[kk][1], bfr, acc[1][ct], 0,0,0);
        }
    }
    #pragma unroll
    for(int rt=0;rt<2;rt++){
        #pragma unroll
        for(int ct=0;ct<8;ct++){
            #pragma unroll
            for(int r=0;r<4;r++){
                int row = w*32 + rt*16 + lg*4 + r;
                int col = ct*16 + lr;
                float v = acc[rt][ct][r] * ms[row*128 + col];
                Pb[(size_t)row*128 + col] = f2bf(v);
            }
        }
    }
}

// ---------------------------------------------------------------- head
__global__ __launch_bounds__(1024) void k_head(
    const float* __restrict__ xo, const float* __restrict__ h1w, const float* __restrict__ h1b,
    const float* __restrict__ h2w, const float* __restrict__ h2b, float* __restrict__ out)
{
    __shared__ float hbuf[NBATCH][32];
    const int t = threadIdx.x;
    const int b = t >> 5, j = t & 31;
    float a = h1b[j];
    #pragma unroll 8
    for(int k=0;k<384;k++) a += xo[b*384+k]*h1w[j*384+k];
    a = a > 0.f ? a : 0.f;
    hbuf[b][j] = a;
    __syncthreads();
    if(j == 0){
        float s = h2b[0];
        #pragma unroll
        for(int k=0;k<32;k++) s += hbuf[b][k]*h2w[k];
        out[b] = s;
    }
}

// ----------------------------------------------------------------
extern "C" void kernel_launch(void* const* d_in, const int* in_sizes, int n_in,
                              void* d_out, int out_size, void* d_ws, size_t ws_size,
                              hipStream_t stream)
{
    (void)in_sizes; (void)n_in; (void)out_size;
    const float* X2  = (const float*)d_in[0];
    const float* M   = (const float*)d_in[1];
    const float* w11 = (const float*)d_in[2];  const float* b11 = (const float*)d_in[3];
    const float* w12 = (const float*)d_in[4];  const float* b12 = (const float*)d_in[5];
    const float* w13 = (const float*)d_in[6];  const float* b13 = (const float*)d_in[7];
    const float* w21 = (const float*)d_in[8];  const float* b21 = (const float*)d_in[9];
    const float* w22 = (const float*)d_in[10]; const float* b22 = (const float*)d_in[11];
    const float* w23 = (const float*)d_in[12]; const float* b23 = (const float*)d_in[13];
    const float* w31 = (const float*)d_in[14]; const float* b31 = (const float*)d_in[15];
    const float* w32 = (const float*)d_in[16]; const float* b32 = (const float*)d_in[17];
    const float* w33 = (const float*)d_in[18]; const float* b33 = (const float*)d_in[19];
    const float* h1w = (const float*)d_in[20]; const float* h1b = (const float*)d_in[21];
    const float* h2w = (const float*)d_in[22]; const float* h2b = (const float*)d_in[23];
    float* out = (float*)d_out;

    char* ws = (char*)d_ws;
    size_t off = 0;
    float* msum = (float*)(ws + off); off += (size_t)NBATCH*HW*4;            // 2 MB
    float* xo   = (float*)(ws + off); off += (size_t)NBATCH*384*4;           // 48 KB
    unsigned short* wp  = (unsigned short*)(ws + off); off += (size_t)WPREP_TOTAL*2; // 624 KB
    off = (off + 255) & ~(size_t)255;
    unsigned short* X2b = (unsigned short*)(ws + off); off += (size_t)NBATCH*64*8192*2; // 32 MB
    off = (off + 255) & ~(size_t)255;

    // 3-buffer rotation (cc writes its swizzled output over the dead plain-B buffer)
    int bc = 32;
    while (bc > 1 && off + 3ull*(size_t)bc*CCH*HW*2 > ws_size) bc >>= 1;
    size_t bufb = (size_t)bc*CCH*HW*2;
    unsigned short* B0 = (unsigned short*)(ws + off);
    unsigned short* B1 = (unsigned short*)(ws + off + bufb);
    unsigned short* B2 = (unsigned short*)(ws + off + 2*bufb);

    const unsigned short* Wab1 = wp + 0;       // z stride 8192
    const unsigned short* Wc1  = wp + 16384;
    const unsigned short* Wab2 = wp + 57344;   // z stride 32768
    const unsigned short* Wc2  = wp + 122880;
    const unsigned short* Wab3 = wp + 188416;  // z stride 32768
    const unsigned short* Wc3  = wp + 253952;

    k_prep<<<(WPREP_TOTAL+255)/256, 256, 0, stream>>>(w11,w12,w13,w21,w22,w23,w31,w32,w33, wp);
    k_xprep<<<dim3(64, NBATCH), 256, 0, stream>>>(X2, X2b);
    k_msum<<<(NBATCH*HW)/256, 256, 0, stream>>>(M, msum);
    hipMemsetAsync(xo, 0, (size_t)NBATCH*384*4, stream);

    for(int b0 = 0; b0 < NBATCH; b0 += bc){
        dim3 gab(128, bc);     // z folded into x: adjacent blocks share X tile (L2)
        dim3 gcc(64, bc);
        dim3 gmat(bc*CCH);
        // ---- block 1
        k_conv<0,1,false,true ,true ><<<gab, 512, 0, stream>>>(Wab1, B0, X2b, b11, b12, msum, M, B0, B1, xo, b0, 0);
        k_bmm<<<gmat, 256, 0, stream>>>(B0, B1, msum, B0, b0);
        k_conv<4,1,true ,true ,true ><<<gcc, 512, 0, stream>>>(Wc1, B0, X2b, b13, b13, msum, M, B1, nullptr, xo, b0, 0);
        // ---- block 2 (X = B1)
        k_conv<0,4,false,false,true ><<<gab, 512, 0, stream>>>(Wab2, B0, B1, b21, b22, msum, M, B0, B2, xo, b0, 0);
        k_bmm<<<gmat, 256, 0, stream>>>(B0, B2, msum, B0, b0);
        k_conv<4,4,true ,false,true ><<<gcc, 512, 0, stream>>>(Wc2, B0, B1, b23, b23, msum, M, B2, nullptr, xo, b0, 128);
        // ---- block 3 (X = B2)
        k_conv<0,4,false,false,true ><<<gab, 512, 0, stream>>>(Wab3, B0, B2, b31, b32, msum, M, B0, B1, xo, b0, 0);
        k_bmm<<<gmat, 256, 0, stream>>>(B0, B1, msum, B0, b0);
        k_conv<4,4,true ,false,false><<<gcc, 512, 0, stream>>>(Wc3, B0, B2, b33, b33, msum, M, B1, nullptr, xo, b0, 256);
    }
    k_head<<<1, 1024, 0, stream>>>(xo, h1w, h1b, h2w, h2b, out);
}